// Round 18
// baseline (29.894 us; speedup 1.0000x reference)
//
#include <hip/hip_runtime.h>

typedef __attribute__((ext_vector_type(8)))  short short8;
typedef __attribute__((ext_vector_type(16))) float f32x16;

#define BATCH 8
#define NPTS  4096
#define TPB   512             // 8 waves; each wave owns 32 query columns
#define NQG   16              // query groups of 256 per (dir,b)
#define REPS  2               // CALIBRATION: main loop runs twice (idempotent)
#define ONEB  0x3F80u         // bf16(1.0)
#define BIASB 0x4080u         // bf16(4.0)
#define BIASF 4.0f

// round-to-nearest-even f32 -> bf16 bits
__device__ __forceinline__ unsigned bfr(float f) {
    unsigned u = __float_as_uint(f);
    return (u + 0x7FFFu + ((u >> 16) & 1u)) >> 16;
}
__device__ __forceinline__ float ubf(unsigned s) {
    return __uint_as_float(s << 16);
}

// CALIBRATION ROUND: exact r15 kernel (22.38 us total) except the main loop
// executes REPS=2 passes over the same 128 tiles in rep-rotated order.
// fminf is idempotent -> output bit-identical; rotation defeats CSE.
// mainloop_time = total(this) - total(r15). Diagnoses whether the ~14 us
// model-vs-measurement gap lives in the MFMA/min3 main loop or in
// prologue/staging/launch overhead.
__global__ __launch_bounds__(TPB) void chamfer_mfma(
    const float* __restrict__ preds,
    const float* __restrict__ gts,
    float* __restrict__ out)
{
    const int blk = blockIdx.x;
    const int qg  = blk & 15;
    const int db  = blk >> 4;        // dir*8 + b
    const int dir = db >> 3;
    const int b   = db & 7;

    const float* Q = dir ? gts   : preds;   // query set (output-indexed)
    const float* T = dir ? preds : gts;     // target set (min'd over)

    __shared__ uint4 sA[2 * NPTS];   // [half][row] A-frags, 128 KiB
    __shared__ float red[TPB / 64];

    const size_t bbase = (size_t)b * NPTS;
    const int lane = threadIdx.x & 63;
    const int wid  = threadIdx.x >> 6;
    const int la   = lane & 31;
    const int h    = lane >> 5;

    // ---- stage all 4096 target rows as A-frags (rows thread-strided so
    // ds_writes are lane-consecutive 16B -> conflict-free)
    for (int j = 0; j < 8; ++j) {
        const int r = threadIdx.x + j * TPB;
        const float* tp = T + (bbase + r) * 3;
        const float X = tp[0], Y = tp[1], Z = tp[2];
        const float px = -2.f * X, py = -2.f * Y, pz = -2.f * Z;
        const float rt = fmaf(X, X, fmaf(Y, Y, Z * Z));
        const unsigned pxh = bfr(px), pyh = bfr(py), pzh = bfr(pz);
        const unsigned pxl = bfr(px - ubf(pxh)), pyl = bfr(py - ubf(pyh)),
                       pzl = bfr(pz - ubf(pzh));
        const unsigned rth = bfr(rt), rtl = bfr(rt - ubf(rth));
        sA[r]        = make_uint4(pxh | (pyh << 16), pzh | (rth << 16),
                                  rtl | (ONEB << 16), ONEB | (ONEB << 16));
        sA[NPTS + r] = make_uint4(pxl | (pyl << 16), pzl | (pxh << 16),
                                  pyh | (pzh << 16), 0u);
    }

    // ---- this lane's B-frag: query col c, half h (k0-7 vs k8-15)
    short8 bfrag;
    {
        const int c = qg * 256 + wid * 32 + la;
        const float* qp = Q + (bbase + c) * 3;
        const float X = qp[0], Y = qp[1], Z = qp[2];
        const float rq = fmaf(X, X, fmaf(Y, Y, Z * Z));
        const unsigned xh = bfr(X), yh = bfr(Y), zh = bfr(Z);
        const unsigned xl = bfr(X - ubf(xh)), yl = bfr(Y - ubf(yh)),
                       zl = bfr(Z - ubf(zh));
        const unsigned rqh = bfr(rq), rql = bfr(rq - ubf(rqh));
        const uint4 b1 = make_uint4(xh | (yh << 16), zh | (ONEB << 16),
                                    ONEB | (rqh << 16), rql | (BIASB << 16));
        const uint4 b2 = make_uint4(xh | (yh << 16), zh | (xl << 16),
                                    yl | (zl << 16), 0u);
        bfrag = __builtin_bit_cast(short8, h ? b2 : b1);
    }

    __syncthreads();

    // ---- main loop: REPS passes over 128 target tiles (rotated order),
    // 2 tiles per iter, register min3 reduce. Identical result to 1 pass.
    const f32x16 zacc = {};
    f32x16 macc;
    #pragma unroll
    for (int i = 0; i < 16; ++i) macc[i] = 3.4e38f;

    const uint4* aBase = sA + h * NPTS + la;
    for (int rep = 0; rep < REPS; ++rep) {
        for (int t = 0; t < NPTS / 32; t += 2) {
            const int tt = (t + rep * 64) & (NPTS / 32 - 1);
            const uint4 A0 = aBase[tt * 32];
            const uint4 A1 = aBase[tt * 32 + 32];
            const f32x16 p0 = __builtin_amdgcn_mfma_f32_32x32x16_bf16(
                __builtin_bit_cast(short8, A0), bfrag, zacc, 0, 0, 0);
            const f32x16 p1 = __builtin_amdgcn_mfma_f32_32x32x16_bf16(
                __builtin_bit_cast(short8, A1), bfrag, zacc, 0, 0, 0);
            #pragma unroll
            for (int i = 0; i < 16; ++i)
                macc[i] = fminf(fminf(p0[i], p1[i]), macc[i]);   // v_min3_f32
        }
    }

    // ---- epilogue: min over the 16 row-slots, then the other lane-half
    const float g0 = fminf(fminf(macc[0],  macc[1]),  macc[2]);
    const float g1 = fminf(fminf(macc[3],  macc[4]),  macc[5]);
    const float g2 = fminf(fminf(macc[6],  macc[7]),  macc[8]);
    const float g3 = fminf(fminf(macc[9],  macc[10]), macc[11]);
    const float g4 = fminf(fminf(macc[12], macc[13]), macc[14]);
    float m = fminf(fminf(fminf(g0, g1), fminf(g2, g3)),
                    fminf(g4, macc[15]));
    m = fminf(m, __shfl_xor(m, 32, 64));

    // ---- sum the 32 col-mins of this wave, then across waves, one atomic
    float s = (lane < 32) ? (m - BIASF) : 0.0f;
    #pragma unroll
    for (int off = 16; off > 0; off >>= 1)
        s += __shfl_down(s, off, 64);

    if (lane == 0) red[wid] = s;
    __syncthreads();
    if (threadIdx.x == 0) {
        float tsum = 0.0f;
        #pragma unroll
        for (int w = 0; w < TPB / 64; ++w) tsum += red[w];
        atomicAdd(out, tsum);
    }
}

extern "C" void kernel_launch(void* const* d_in, const int* in_sizes, int n_in,
                              void* d_out, int out_size, void* d_ws, size_t ws_size,
                              hipStream_t stream) {
    const float* preds = (const float*)d_in[0];
    const float* gts   = (const float*)d_in[1];
    float* out = (float*)d_out;

    hipMemsetAsync(out, 0, sizeof(float), stream);
    chamfer_mfma<<<dim3(2 * BATCH * NQG), TPB, 0, stream>>>(preds, gts, out);
}

// Round 19
// 20.240 us; speedup vs baseline: 1.4770x; 1.4770x over previous
//
#include <hip/hip_runtime.h>

typedef __attribute__((ext_vector_type(8)))  short short8;
typedef __attribute__((ext_vector_type(16))) float f32x16;

#define BATCH 8
#define NPTS  4096
#define NTS   4               // target splits per (dir,b)
#define TROWS (NPTS / NTS)    // 1024 target rows per block
#define TPB   512             // 8 waves; each wave owns 32 query columns
#define NQG   16              // query groups of 256 per (dir,b)
#define NQTOT (2 * BATCH * NPTS)   // 65536 total queries
#define ONEB  0x3F80u         // bf16(1.0)
#define BIASB 0x4080u         // bf16(4.0)
#define BIASF 4.0f

// round-to-nearest-even f32 -> bf16 bits
__device__ __forceinline__ unsigned bfr(float f) {
    unsigned u = __float_as_uint(f);
    return (u + 0x7FFFu + ((u >> 16) & 1u)) >> 16;
}
__device__ __forceinline__ float ubf(unsigned s) {
    return __uint_as_float(s << 16);
}

// MFMA chamfer, round-19. r18 calibration: main loop = 7.5 us, non-loop =
// ~15 us (staging at 1 block/CU, ramp, memset dispatch). Fix: 4-way target
// split -> 32 KiB LDS (2 blocks/CU resident, 4 waves/SIMD for MFMA-latency
// hiding), 1024 rows staged per block (4x less prologue), 1024 blocks
// (tail amortized). Partial col-mins -> part[] via plain coalesced stores
// (r8 pattern, no atomics); K1-block0 zeroes out (no memset dispatch).
// Encoding unchanged (verified absmax 0.0 since r14): P = |t-q|^2 + BIAS,
// K=16 rank factorization, hi k0-7 (lanes<32), lo k8-15 (lanes>=32), one
// mfma_f32_32x32x16_bf16 per 32x32 tile, register v_min3_f32 reduce.
__global__ __launch_bounds__(TPB, 4) void chamfer_mfma(
    const float* __restrict__ preds,
    const float* __restrict__ gts,
    float* __restrict__ part,    // [NTS][NQTOT]
    float* __restrict__ out)
{
    const int blk = blockIdx.x;
    const int ts  = blk & (NTS - 1);
    const int qg  = (blk >> 2) & 15;
    const int db  = blk >> 6;        // dir*8 + b
    const int dir = db >> 3;
    const int b   = db & 7;

    if (blk == 0 && threadIdx.x == 0) out[0] = 0.0f;

    const float* Q = dir ? gts   : preds;   // query set (output-indexed)
    const float* T = dir ? preds : gts;     // target set (min'd over)

    __shared__ uint4 sA[2 * TROWS];  // [half][row] A-frags, 32 KiB

    const size_t bbase = (size_t)b * NPTS;
    const int lane = threadIdx.x & 63;
    const int wid  = threadIdx.x >> 6;
    const int la   = lane & 31;
    const int h    = lane >> 5;      // 0: k0-7 (hi), 1: k8-15 (lo)

    // ---- stage this block's 1024 target rows as A-frags (2 rows/thread,
    // lane-consecutive 16B ds_writes -> conflict-free)
    for (int j = 0; j < TROWS / TPB; ++j) {
        const int r = threadIdx.x + j * TPB;
        const float* tp = T + (bbase + ts * TROWS + r) * 3;
        const float X = tp[0], Y = tp[1], Z = tp[2];
        const float px = -2.f * X, py = -2.f * Y, pz = -2.f * Z;
        const float rt = fmaf(X, X, fmaf(Y, Y, Z * Z));
        const unsigned pxh = bfr(px), pyh = bfr(py), pzh = bfr(pz);
        const unsigned pxl = bfr(px - ubf(pxh)), pyl = bfr(py - ubf(pyh)),
                       pzl = bfr(pz - ubf(pzh));
        const unsigned rth = bfr(rt), rtl = bfr(rt - ubf(rth));
        sA[r]         = make_uint4(pxh | (pyh << 16), pzh | (rth << 16),
                                   rtl | (ONEB << 16), ONEB | (ONEB << 16));
        sA[TROWS + r] = make_uint4(pxl | (pyl << 16), pzl | (pxh << 16),
                                   pyh | (pzh << 16), 0u);
    }

    // ---- this lane's B-frag: query col c, half h (k0-7 vs k8-15)
    short8 bfrag;
    const int c = qg * 256 + wid * 32 + la;
    {
        const float* qp = Q + (bbase + c) * 3;
        const float X = qp[0], Y = qp[1], Z = qp[2];
        const float rq = fmaf(X, X, fmaf(Y, Y, Z * Z));
        const unsigned xh = bfr(X), yh = bfr(Y), zh = bfr(Z);
        const unsigned xl = bfr(X - ubf(xh)), yl = bfr(Y - ubf(yh)),
                       zl = bfr(Z - ubf(zh));
        const unsigned rqh = bfr(rq), rql = bfr(rq - ubf(rqh));
        const uint4 b1 = make_uint4(xh | (yh << 16), zh | (ONEB << 16),
                                    ONEB | (rqh << 16), rql | (BIASB << 16));
        const uint4 b2 = make_uint4(xh | (yh << 16), zh | (xl << 16),
                                    yl | (zl << 16), 0u);
        bfrag = __builtin_bit_cast(short8, h ? b2 : b1);
    }

    __syncthreads();

    // ---- main loop: 32 target tiles, 2 per iter, register min3 reduce
    const f32x16 zacc = {};
    f32x16 macc;
    #pragma unroll
    for (int i = 0; i < 16; ++i) macc[i] = 3.4e38f;

    const uint4* aBase = sA + h * TROWS + la;
    for (int t = 0; t < TROWS / 32; t += 2) {
        const uint4 A0 = aBase[t * 32];
        const uint4 A1 = aBase[t * 32 + 32];
        const f32x16 p0 = __builtin_amdgcn_mfma_f32_32x32x16_bf16(
            __builtin_bit_cast(short8, A0), bfrag, zacc, 0, 0, 0);
        const f32x16 p1 = __builtin_amdgcn_mfma_f32_32x32x16_bf16(
            __builtin_bit_cast(short8, A1), bfrag, zacc, 0, 0, 0);
        #pragma unroll
        for (int i = 0; i < 16; ++i)
            macc[i] = fminf(fminf(p0[i], p1[i]), macc[i]);   // v_min3_f32
    }

    // ---- epilogue: min over the 16 row-slots, fold lane halves, store
    const float g0 = fminf(fminf(macc[0],  macc[1]),  macc[2]);
    const float g1 = fminf(fminf(macc[3],  macc[4]),  macc[5]);
    const float g2 = fminf(fminf(macc[6],  macc[7]),  macc[8]);
    const float g3 = fminf(fminf(macc[9],  macc[10]), macc[11]);
    const float g4 = fminf(fminf(macc[12], macc[13]), macc[14]);
    float m = fminf(fminf(fminf(g0, g1), fminf(g2, g3)),
                    fminf(g4, macc[15]));
    m = fminf(m, __shfl_xor(m, 32, 64));

    // coalesced partial store: part[ts][db*4096 + c]
    if (lane < 32)
        part[(size_t)ts * NQTOT + (size_t)db * NPTS + c] = m;
}

// Stage 2: one thread per query; min over the 4 target-split partials,
// subtract BIAS, block-reduce, one atomicAdd per block (out zeroed by K1).
#define TPB2 256
__global__ __launch_bounds__(TPB2) void chamfer_stage2(
    const float* __restrict__ part,
    float* __restrict__ out)
{
    const int g = blockIdx.x * TPB2 + threadIdx.x;   // [0, 65536)

    const float m01 = fminf(part[g],             part[NQTOT + g]);
    const float m23 = fminf(part[2 * NQTOT + g], part[3 * NQTOT + g]);
    float s = fminf(m01, m23) - BIASF;

    #pragma unroll
    for (int off = 32; off > 0; off >>= 1)
        s += __shfl_down(s, off, 64);

    __shared__ float red[TPB2 / 64];
    const int lane = threadIdx.x & 63;
    const int wid  = threadIdx.x >> 6;
    if (lane == 0) red[wid] = s;
    __syncthreads();
    if (threadIdx.x == 0) {
        float t = 0.0f;
        #pragma unroll
        for (int w = 0; w < TPB2 / 64; ++w) t += red[w];
        atomicAdd(out, t);
    }
}

extern "C" void kernel_launch(void* const* d_in, const int* in_sizes, int n_in,
                              void* d_out, int out_size, void* d_ws, size_t ws_size,
                              hipStream_t stream) {
    const float* preds = (const float*)d_in[0];
    const float* gts   = (const float*)d_in[1];
    float* out  = (float*)d_out;
    float* part = (float*)d_ws;   // NTS x 65536 floats = 1 MiB

    // 2 dispatches, no memsets: K1 block 0 zeroes out; part fully written
    // by K1 before K2 reads it (kernel-boundary visibility).
    chamfer_mfma<<<dim3(2 * BATCH * NQG * NTS), TPB, 0, stream>>>(preds, gts, part, out);
    chamfer_stage2<<<dim3(NQTOT / TPB2), TPB2, 0, stream>>>(part, out);
}